// Round 15
// baseline (76.397 us; speedup 1.0000x reference)
//
#include <hip/hip_runtime.h>

typedef __attribute__((ext_vector_type(4))) float f32x4;
typedef __attribute__((ext_vector_type(8))) short bf16x8;

__device__ __forceinline__ short bf16_rne(float f) {
    unsigned int u = __float_as_uint(f);
    u += 0x7FFFu + ((u >> 16) & 1u);
    return (short)(u >> 16);
}

// G=16, in_g=out_g=64. rows-per-group = 32768, total rows = 524288.
// Row r: 64 contiguous floats of x; group g = r>>15.
// out[(g*64+o)*32768 + (r & 32767)].
// CHANNEL-SPLIT wave (R15): each wave = 64 rows x 32 channels (2 o-tiles).
// 16384 waves = 4096 blocks x 4. Sibling waves (same rows, other 32 channels)
// are co-resident in the same block -> x re-read hits L2.
// Halves per-wave lifetime vs R10 -> ~2x occupancy generations (R10 ran at
// 27% time-avg occupancy, latency-exposed).
// NUMERICS: R1's validated path (absmax 0.031): A = bf16(xhat*gamma+beta),
// B = bf16(W), bias in fp32 epilogue.
// STORES (R10-verified, FROZEN): defer all 4 tiles in vout regs; per channel
// store its FULL 256-B granule-aligned span in 4 back-to-back nt stores at
// wave end. R11: persistent-wave chunk bursts re-amplify writes (150->210).
// R13/R14: 2-deep prefetch costs VGPR/occupancy, no gain. 1-deep kept.

__global__ __launch_bounds__(256, 2)
void gln_mfma_kernel(const float* __restrict__ x,
                     const float* __restrict__ gamma,
                     const float* __restrict__ beta,
                     const float* __restrict__ W,
                     const float* __restrict__ bias,
                     float* __restrict__ out)
{
    const int tid  = threadIdx.x;
    const int lane = tid & 63;
    const int w    = blockIdx.x * 4 + (tid >> 6);   // 0..16383
    const int p    = w >> 1;                         // row-chunk id 0..8191
    const int h    = w & 1;                          // channel half 0/1
    const int g    = p >> 9;                         // 16 groups
    const int rr0  = (p & 511) << 6;                 // row-in-group base (64 rows)

    const int l15 = lane & 15;
    const int l4  = lane >> 4;      // 0..3
    const int ks  = l4 * 8;         // k-slice base within a 32-wide K chunk

    const float* xg = x   + (size_t)g * 32768 * 64;
    float* outg     = out + (size_t)g * 64 * 32768;

    // ---- B fragments for this wave's 2 o-tiles (W first in vmcnt FIFO) ----
    bf16x8 bfrag[2][2];
    {
        const float* Wg = W + (size_t)(g * 64) * 64;
        #pragma unroll
        for (int oti = 0; oti < 2; ++oti) {
            const float* wrow = Wg + (size_t)((h * 2 + oti) * 16 + l15) * 64;
            #pragma unroll
            for (int kc = 0; kc < 2; ++kc) {
                f32x4 w0 = *(const f32x4*)(wrow + kc * 32 + ks);
                f32x4 w1 = *(const f32x4*)(wrow + kc * 32 + ks + 4);
                bf16x8 f;
                #pragma unroll
                for (int j = 0; j < 4; ++j) { f[j] = bf16_rne(w0[j]); f[j + 4] = bf16_rne(w1[j]); }
                bfrag[oti][kc] = f;
            }
        }
    }

    // ---- gamma/beta for this lane's 16 k positions ----
    float gk[16], bk[16];
    {
        const float* gp = gamma + g * 64;
        const float* bp = beta  + g * 64;
        #pragma unroll
        for (int kc = 0; kc < 2; ++kc) {
            f32x4 g0 = *(const f32x4*)(gp + kc * 32 + ks);
            f32x4 g1 = *(const f32x4*)(gp + kc * 32 + ks + 4);
            f32x4 b0 = *(const f32x4*)(bp + kc * 32 + ks);
            f32x4 b1 = *(const f32x4*)(bp + kc * 32 + ks + 4);
            #pragma unroll
            for (int j = 0; j < 4; ++j) {
                gk[kc * 8 + j] = g0[j]; gk[kc * 8 + 4 + j] = g1[j];
                bk[kc * 8 + j] = b0[j]; bk[kc * 8 + 4 + j] = b1[j];
            }
        }
    }

    float bo[2];
    #pragma unroll
    for (int oti = 0; oti < 2; ++oti) bo[oti] = bias[g * 64 + (h * 2 + oti) * 16 + l15];

    // ---- main loop: 4 tiles of 16 rows, 1-deep register prefetch ----
    f32x4 buf[2][4];
    {
        const float* rowp = xg + (size_t)(rr0 + l15) * 64;
        buf[0][0] = *(const f32x4*)(rowp + ks);
        buf[0][1] = *(const f32x4*)(rowp + ks + 4);
        buf[0][2] = *(const f32x4*)(rowp + 32 + ks);
        buf[0][3] = *(const f32x4*)(rowp + 32 + ks + 4);
    }

    f32x4 vout[4][2];                   // [tile][oti] — all stores deferred

    #pragma unroll
    for (int t = 0; t < 4; ++t) {
        if (t + 1 < 4) {
            const float* rowp = xg + (size_t)(rr0 + (t + 1) * 16 + l15) * 64;
            buf[(t + 1) & 1][0] = *(const f32x4*)(rowp + ks);
            buf[(t + 1) & 1][1] = *(const f32x4*)(rowp + ks + 4);
            buf[(t + 1) & 1][2] = *(const f32x4*)(rowp + 32 + ks);
            buf[(t + 1) & 1][3] = *(const f32x4*)(rowp + 32 + ks + 4);
        }

        // LN stats over the row (4 lanes share a row: xor 16, 32)
        float s = 0.f, s2 = 0.f;
        #pragma unroll
        for (int i = 0; i < 4; ++i) {
            #pragma unroll
            for (int j = 0; j < 4; ++j) {
                float v = buf[t & 1][i][j];
                s += v; s2 += v * v;
            }
        }
        s  += __shfl_xor(s, 16, 64);  s  += __shfl_xor(s, 32, 64);
        s2 += __shfl_xor(s2, 16, 64); s2 += __shfl_xor(s2, 32, 64);
        const float mu   = s * (1.0f / 64.0f);
        const float var  = s2 * (1.0f / 64.0f) - mu * mu;
        const float rstd = rsqrtf(var + 1e-6f);

        // normalize + affine -> A fragments (bf16)   [R1 numerics]
        bf16x8 a0, a1;
        #pragma unroll
        for (int j = 0; j < 8; ++j) {
            float c1 = rstd * gk[j];
            float v  = buf[t & 1][j >> 2][j & 3] * c1 + (bk[j] - mu * c1);
            a0[j] = bf16_rne(v);
        }
        #pragma unroll
        for (int j = 0; j < 8; ++j) {
            float c1 = rstd * gk[8 + j];
            float v  = buf[t & 1][2 + (j >> 2)][j & 3] * c1 + (bk[8 + j] - mu * c1);
            a1[j] = bf16_rne(v);
        }

        #pragma unroll
        for (int oti = 0; oti < 2; ++oti) {
            f32x4 acc = {0.f, 0.f, 0.f, 0.f};
            acc = __builtin_amdgcn_mfma_f32_16x16x32_bf16(a0, bfrag[oti][0], acc, 0, 0, 0);
            acc = __builtin_amdgcn_mfma_f32_16x16x32_bf16(a1, bfrag[oti][1], acc, 0, 0, 0);
            #pragma unroll
            for (int q = 0; q < 4; ++q) acc[q] += bo[oti];
            vout[t][oti] = acc;
        }
    }

    // ---- epilogue: per channel, its FULL 256 B span in 4 adjacent nt stores ----
    #pragma unroll
    for (int oti = 0; oti < 2; ++oti) {
        float* base = outg + (size_t)((h * 2 + oti) * 16 + l15) * 32768 + rr0 + l4 * 4;
        #pragma unroll
        for (int t = 0; t < 4; ++t) {
            __builtin_nontemporal_store(vout[t][oti], (f32x4*)(base + t * 16));
        }
    }
}

extern "C" void kernel_launch(void* const* d_in, const int* in_sizes, int n_in,
                              void* d_out, int out_size, void* d_ws, size_t ws_size,
                              hipStream_t stream) {
    const float* x     = (const float*)d_in[0];
    const float* gamma = (const float*)d_in[1];
    const float* beta  = (const float*)d_in[2];
    const float* W     = (const float*)d_in[3];
    const float* b     = (const float*)d_in[4];
    float* out = (float*)d_out;

    dim3 grid(4096), block(256);
    hipLaunchKernelGGL(gln_mfma_kernel, grid, block, 0, stream, x, gamma, beta, W, b, out);
}

// Round 16
// 63.584 us; speedup vs baseline: 1.2015x; 1.2015x over previous
//
#include <hip/hip_runtime.h>

typedef __attribute__((ext_vector_type(4))) float f32x4;
typedef __attribute__((ext_vector_type(8))) short bf16x8;

__device__ __forceinline__ short bf16_rne(float f) {
    unsigned int u = __float_as_uint(f);
    u += 0x7FFFu + ((u >> 16) & 1u);
    return (short)(u >> 16);
}

// G=16, in_g=out_g=64. rows-per-group = 32768, total rows = 524288.
// Row r: 64 contiguous floats of x; group g = r>>15.
// out[(g*64+o)*32768 + (r & 32767)].
// PERSISTENT wave, FAR-apart chunks (R16): wave w handles chunks c0 and
// c0+256 of group g (byte offsets 256*c0 and 256*c0+64KB per channel row —
// granule-independent). 4096 waves = 1024 blocks x 4 (exactly 4 blocks/CU).
// One W/gamma/beta preamble serves both chunks.
// R11 (adjacent chunks c,c+1) re-amplified WRITE 150->210: the pair forms one
// 512B granule split in time -> granule re-split. Far chunks avoid that.
// NUMERICS: R1's validated path (absmax 0.031): A = bf16(xhat*gamma+beta),
// B = bf16(W), bias in fp32 epilogue.
// STORES (R10-verified, FROZEN): per chunk, defer 4 tiles in vout; per channel
// store its FULL 256-B span in 4 back-to-back nt stores. Cross-chunk
// prefetch: chunk-1 tile-0 loads issue BEFORE chunk-0's store burst
// (vmcnt FIFO: younger stores don't delay waiting on those loads).
// R13/R14: 2-deep prefetch costs VGPR, no gain -> 1-deep kept.

__global__ __launch_bounds__(256, 2)
void gln_mfma_kernel(const float* __restrict__ x,
                     const float* __restrict__ gamma,
                     const float* __restrict__ beta,
                     const float* __restrict__ W,
                     const float* __restrict__ bias,
                     float* __restrict__ out)
{
    const int tid  = threadIdx.x;
    const int lane = tid & 63;
    const int w    = blockIdx.x * 4 + (tid >> 6);   // 0..4095
    const int g    = w >> 8;                         // 16 groups, 256 waves each
    const int c0   = w & 255;                        // chunk 0 id in group
    const int rr0_0 = c0 << 6;                       // chunk 0 row base
    const int rr0_1 = rr0_0 + (256 << 6);            // chunk 1 row base (+16384)

    const int l15 = lane & 15;
    const int l4  = lane >> 4;      // 0..3
    const int ks  = l4 * 8;         // k-slice base within a 32-wide K chunk

    const float* xg = x   + (size_t)g * 32768 * 64;
    float* outg     = out + (size_t)g * 64 * 32768;

    // ---- B fragments: lane elem j = W[g][ot*16+l15][kc*32+ks+j] ----
    bf16x8 bfrag[4][2];
    {
        const float* Wg = W + (size_t)(g * 64) * 64;
        #pragma unroll
        for (int ot = 0; ot < 4; ++ot) {
            const float* wrow = Wg + (size_t)(ot * 16 + l15) * 64;
            #pragma unroll
            for (int kc = 0; kc < 2; ++kc) {
                f32x4 w0 = *(const f32x4*)(wrow + kc * 32 + ks);
                f32x4 w1 = *(const f32x4*)(wrow + kc * 32 + ks + 4);
                bf16x8 f;
                #pragma unroll
                for (int j = 0; j < 4; ++j) { f[j] = bf16_rne(w0[j]); f[j + 4] = bf16_rne(w1[j]); }
                bfrag[ot][kc] = f;
            }
        }
    }

    // ---- gamma/beta for this lane's 16 k positions ----
    float gk[16], bk[16];
    {
        const float* gp = gamma + g * 64;
        const float* bp = beta  + g * 64;
        #pragma unroll
        for (int kc = 0; kc < 2; ++kc) {
            f32x4 g0 = *(const f32x4*)(gp + kc * 32 + ks);
            f32x4 g1 = *(const f32x4*)(gp + kc * 32 + ks + 4);
            f32x4 b0 = *(const f32x4*)(bp + kc * 32 + ks);
            f32x4 b1 = *(const f32x4*)(bp + kc * 32 + ks + 4);
            #pragma unroll
            for (int j = 0; j < 4; ++j) {
                gk[kc * 8 + j] = g0[j]; gk[kc * 8 + 4 + j] = g1[j];
                bk[kc * 8 + j] = b0[j]; bk[kc * 8 + 4 + j] = b1[j];
            }
        }
    }

    float bo[4];
    #pragma unroll
    for (int ot = 0; ot < 4; ++ot) bo[ot] = bias[g * 64 + ot * 16 + l15];

    // ---- persistent loop: 2 far-apart chunks x 4 tiles, 1-deep prefetch ----
    f32x4 buf[2][4];
    {
        const float* rowp = xg + (size_t)(rr0_0 + l15) * 64;
        buf[0][0] = *(const f32x4*)(rowp + ks);
        buf[0][1] = *(const f32x4*)(rowp + ks + 4);
        buf[0][2] = *(const f32x4*)(rowp + 32 + ks);
        buf[0][3] = *(const f32x4*)(rowp + 32 + ks + 4);
    }

    #pragma unroll
    for (int cc = 0; cc < 2; ++cc) {
        const int rrc = cc ? rr0_1 : rr0_0;
        f32x4 vout[4][4];               // [tile][ot] — stores deferred per chunk

        #pragma unroll
        for (int t = 0; t < 4; ++t) {
            // prefetch next global tile (crosses into chunk 1 before the
            // chunk-0 store burst; loads are older than the burst's stores)
            const int n = cc * 4 + t + 1;
            if (n < 8) {
                const int rrn = (n < 4) ? (rr0_0 + n * 16) : (rr0_1 + (n - 4) * 16);
                const float* rowp = xg + (size_t)(rrn + l15) * 64;
                buf[n & 1][0] = *(const f32x4*)(rowp + ks);
                buf[n & 1][1] = *(const f32x4*)(rowp + ks + 4);
                buf[n & 1][2] = *(const f32x4*)(rowp + 32 + ks);
                buf[n & 1][3] = *(const f32x4*)(rowp + 32 + ks + 4);
            }
            const int tb = (cc * 4 + t) & 1;

            // LN stats over the row (4 lanes share a row: xor 16, 32)
            float s = 0.f, s2 = 0.f;
            #pragma unroll
            for (int i = 0; i < 4; ++i) {
                #pragma unroll
                for (int j = 0; j < 4; ++j) {
                    float v = buf[tb][i][j];
                    s += v; s2 += v * v;
                }
            }
            s  += __shfl_xor(s, 16, 64);  s  += __shfl_xor(s, 32, 64);
            s2 += __shfl_xor(s2, 16, 64); s2 += __shfl_xor(s2, 32, 64);
            const float mu   = s * (1.0f / 64.0f);
            const float var  = s2 * (1.0f / 64.0f) - mu * mu;
            const float rstd = rsqrtf(var + 1e-6f);

            // normalize + affine -> A fragments (bf16)   [R1 numerics]
            bf16x8 a0, a1;
            #pragma unroll
            for (int j = 0; j < 8; ++j) {
                float c1 = rstd * gk[j];
                float v  = buf[tb][j >> 2][j & 3] * c1 + (bk[j] - mu * c1);
                a0[j] = bf16_rne(v);
            }
            #pragma unroll
            for (int j = 0; j < 8; ++j) {
                float c1 = rstd * gk[8 + j];
                float v  = buf[tb][2 + (j >> 2)][j & 3] * c1 + (bk[8 + j] - mu * c1);
                a1[j] = bf16_rne(v);
            }

            #pragma unroll
            for (int ot = 0; ot < 4; ++ot) {
                f32x4 acc = {0.f, 0.f, 0.f, 0.f};
                acc = __builtin_amdgcn_mfma_f32_16x16x32_bf16(a0, bfrag[ot][0], acc, 0, 0, 0);
                acc = __builtin_amdgcn_mfma_f32_16x16x32_bf16(a1, bfrag[ot][1], acc, 0, 0, 0);
                #pragma unroll
                for (int q = 0; q < 4; ++q) acc[q] += bo[ot];
                vout[t][ot] = acc;
            }
        }

        // ---- chunk epilogue: per channel, FULL 256 B span, 4 adjacent nt stores ----
        #pragma unroll
        for (int ot = 0; ot < 4; ++ot) {
            float* base = outg + (size_t)(ot * 16 + l15) * 32768 + rrc + l4 * 4;
            #pragma unroll
            for (int t = 0; t < 4; ++t) {
                __builtin_nontemporal_store(vout[t][ot], (f32x4*)(base + t * 16));
            }
        }
    }
}

extern "C" void kernel_launch(void* const* d_in, const int* in_sizes, int n_in,
                              void* d_out, int out_size, void* d_ws, size_t ws_size,
                              hipStream_t stream) {
    const float* x     = (const float*)d_in[0];
    const float* gamma = (const float*)d_in[1];
    const float* beta  = (const float*)d_in[2];
    const float* W     = (const float*)d_in[3];
    const float* b     = (const float*)d_in[4];
    float* out = (float*)d_out;

    dim3 grid(1024), block(256);
    hipLaunchKernelGGL(gln_mfma_kernel, grid, block, 0, stream, x, gamma, beta, W, b, out);
}